// Round 1
// baseline (731.252 us; speedup 1.0000x reference)
//
#include <hip/hip_runtime.h>
#include <math.h>
#include <stdint.h>

#define BB 64
#define SS 512
#define HH 1024
#define TT 21

// DPP-based partial reduce within row of 16, then cross-row shuffles.
template <int CTRL>
__device__ __forceinline__ float dpp_add(float v) {
  int t = __builtin_amdgcn_update_dpp(0, __float_as_int(v), CTRL, 0xF, 0xF, true);
  return v + __int_as_float(t);
}
__device__ __forceinline__ float wave_sum(float v) {
  v = dpp_add<0x121>(v);  // row_ror:1
  v = dpp_add<0x122>(v);  // row_ror:2
  v = dpp_add<0x124>(v);  // row_ror:4
  v = dpp_add<0x128>(v);  // row_ror:8
  v += __shfl_xor(v, 16);
  v += __shfl_xor(v, 32);
  return v;
}

#define DOT4(A, H, WV)    \
  A = fmaf(H.x, WV.x, A); \
  A = fmaf(H.y, WV.y, A); \
  A = fmaf(H.z, WV.z, A); \
  A = fmaf(H.w, WV.w, A)

// ---------------- Kernel 1: emissions = hs @ W^T + bias ----------------
// Round-0 (this session) rewrite: the old version split K across lanes and
// paid a DPP+ds_swizzle wave reduction per output (reduction insts ~= FMA
// insts, DS latency chains, 84KB LDS W -> 1 block/CU). New structure:
//   thread = (row, K-eighth), 21 accumulators in registers, NO cross-lane
//   reduction. hs streamed as float4 (lanes 0..7 cover 128B contiguous),
//   W read as 128-B broadcast loads (L2-hot). Tiny LDS for 8-way combine
//   + coalesced contiguous store.
#define RPB 32  // rows per block (256 threads / 8 K-phases)
__global__ __launch_bounds__(256, 4) void k_emis(const float* __restrict__ hs,
                                                 const float* __restrict__ W,
                                                 const float* __restrict__ bias,
                                                 float* __restrict__ emis) {
  __shared__ float part[256 * TT];  // 21504 B, stride 21 -> conflict-free
  const int tid = threadIdx.x;
  const int q = tid & 7;   // K-phase 0..7 (covers k4 = 8*i + q)
  const int r = tid >> 3;  // row-in-block 0..31
  const size_t row = (size_t)blockIdx.x * RPB + r;
  const float4* hp = (const float4*)(hs + row * HH);

  float acc[TT];
#pragma unroll
  for (int t = 0; t < TT; ++t) acc[t] = 0.f;

  float4 h = hp[q];  // i = 0 prefetched
#pragma unroll 2
  for (int i = 0; i < 32; ++i) {
    const float4 hc = h;
    if (i < 31) h = hp[(i + 1) * 8 + q];  // prefetch next chunk of this row
    const float* wb = W + (size_t)(i * 8 + q) * 4;
#pragma unroll
    for (int t = 0; t < TT; ++t) {
      const float4 w = *(const float4*)(wb + t * HH);  // 128B/inst broadcast
      DOT4(acc[t], hc, w);
    }
  }

#pragma unroll
  for (int t = 0; t < TT; ++t) part[tid * TT + t] = acc[t];
  __syncthreads();

  // combine the 8 K-phase partials; outputs of this block are 672
  // contiguous floats -> coalesced store
  for (int o = tid; o < RPB * TT; o += 256) {
    const int rr = o / TT;
    const int t = o - rr * TT;
    const float* pp = part + (size_t)(rr * 8) * TT + t;
    float s = ((pp[0] + pp[TT]) + (pp[2 * TT] + pp[3 * TT])) +
              ((pp[4 * TT] + pp[5 * TT]) + (pp[6 * TT] + pp[7 * TT]));
    emis[(size_t)blockIdx.x * RPB * TT + o] = s + bias[t];
  }
}

// ---------------- Kernel 2: CRF forward scan + Viterbi ----------------
// (byte-identical to the verified round-6 kernel)
__global__ __launch_bounds__(64, 1) void k_scan(const float* __restrict__ emis,
                                                const int* __restrict__ mask,
                                                const float* __restrict__ trans,
                                                const float* __restrict__ sv,
                                                const float* __restrict__ ev,
                                                float* __restrict__ logZ,
                                                float* __restrict__ pred) {
  __shared__ float sE[2 * SS * TT];        // 84 KiB
  __shared__ int sM[2 * SS];               // 4 KiB
  __shared__ unsigned char bp[2][SS][32];  // 32 KiB (viterbi only)
  __shared__ unsigned char sTag[2][SS];    // 1 KiB  (viterbi only)
  __shared__ float sV[2][24];              // broadcast buffer
  const int lane = threadIdx.x;
  const int g = lane >> 5;
  const int j = lane & 31;
  const bool act = (j < TT);
  const int jj = act ? j : 0;
  const int b0 = (blockIdx.x & 31) * 2;
  const int b = b0 + g;

  if (lane < 48) ((float*)sV)[lane] = 0.f;  // zero incl. pad entries 21..23

  // ---- stage emissions + mask for both batches of this block ----
  {
    const float4* src = (const float4*)(emis + (size_t)b0 * SS * TT);
    float4* dst = (float4*)sE;
    for (int i = lane; i < 2 * SS * TT / 4; i += 64) dst[i] = src[i];
    const int* msrc = mask + b0 * SS;
    for (int i = lane; i < 2 * SS; i += 64) sM[i] = msrc[i];
  }
  __syncthreads();
  const float* myE = sE + g * SS * TT;
  const int* myM = sM + g * SS;

  if (blockIdx.x < 32) {
    // ---- CRF logsumexp scan (exp domain, v = exp(alpha - C)) ----
    float E[TT];
#pragma unroll
    for (int i = 0; i < TT; ++i) E[i] = __expf(trans[i * TT + jj]);
    float v = act ? __expf(sv[jj] + myE[jj]) : 0.f;
    float C = 0.f;
    float ge_nx = __expf(myE[TT + jj]);
    int mk_nx = myM[1];
    for (int t = 1; t < SS; ++t) {
      const float ge = ge_nx;
      const int mk = mk_nx;
      const int tn = (t + 1 < SS) ? (t + 1) : (SS - 1);
      ge_nx = __expf(myE[tn * TT + jj]);
      mk_nx = myM[tn];
      if (act) sV[g][j] = v;
      __syncthreads();  // single wave: cheap; orders write->reads
      const float4* vb = (const float4*)sV[g];
      float4 V0 = vb[0], V1 = vb[1], V2 = vb[2], V3 = vb[3], V4 = vb[4], V5 = vb[5];
      float scale = 1.0f;
      if ((t & 7) == 0) {
        // renorm: max of all 21 v's (in registers, uniform across lanes)
        float m = fmaxf(fmaxf(fmaxf(V0.x, V0.y), fmaxf(V0.z, V0.w)),
                        fmaxf(fmaxf(V1.x, V1.y), fmaxf(V1.z, V1.w)));
        m = fmaxf(m, fmaxf(fmaxf(V2.x, V2.y), fmaxf(V2.z, V2.w)));
        m = fmaxf(m, fmaxf(fmaxf(V3.x, V3.y), fmaxf(V3.z, V3.w)));
        m = fmaxf(m, fmaxf(fmaxf(V4.x, V4.y), fmaxf(V4.z, V4.w)));
        m = fmaxf(m, V5.x);
        int ex = (int)((__float_as_uint(m) >> 23) & 255u) - 127;
        scale = __uint_as_float((unsigned)(127 - ex) << 23);  // 2^-ex exact
        C += (float)ex * 0.6931471805599453f;
        v *= scale;  // keep masked lanes consistent with C
      }
      // q chains: identical summation order to the verified round-6 kernel
      float q0 = V0.x * E[0], q1 = V0.y * E[1], q2 = V0.z * E[2];
      q0 = fmaf(V0.w, E[3], q0);  q1 = fmaf(V1.x, E[4], q1);  q2 = fmaf(V1.y, E[5], q2);
      q0 = fmaf(V1.z, E[6], q0);  q1 = fmaf(V1.w, E[7], q1);  q2 = fmaf(V2.x, E[8], q2);
      q0 = fmaf(V2.y, E[9], q0);  q1 = fmaf(V2.z, E[10], q1); q2 = fmaf(V2.w, E[11], q2);
      q0 = fmaf(V3.x, E[12], q0); q1 = fmaf(V3.y, E[13], q1); q2 = fmaf(V3.z, E[14], q2);
      q0 = fmaf(V3.w, E[15], q0); q1 = fmaf(V4.x, E[16], q1); q2 = fmaf(V4.y, E[17], q2);
      q0 = fmaf(V4.z, E[18], q0); q1 = fmaf(V4.w, E[19], q1); q2 = fmaf(V5.x, E[20], q2);
      float vn = ((q0 + q1 + q2) * scale) * ge;
      v = (act && mk) ? vn : v;
    }
    float wv = act ? v * __expf(ev[jj]) : 0.f;
#pragma unroll
    for (int d = 16; d >= 1; d >>= 1) wv += __shfl_xor(wv, d);
    if (j == 0) logZ[b] = C + __logf(wv);
  } else {
    // ---- Viterbi: LDS broadcast + 3 argmax chains + tie-safe merge ----
    float Tc[TT];
#pragma unroll
    for (int i = 0; i < TT; ++i) Tc[i] = trans[i * TT + jj];
    float sc = act ? (sv[jj] + myE[jj]) : -3.0e38f;
    float e_nx = myE[TT + jj];
    int mk_nx = myM[1];
    for (int t = 1; t < SS; ++t) {
      const float e = e_nx;
      const int mk = mk_nx;
      const int tn = (t + 1 < SS) ? (t + 1) : (SS - 1);
      e_nx = myE[tn * TT + jj];
      mk_nx = myM[tn];
      if (act) sV[g][j] = sc;
      __syncthreads();
      const float4* vb = (const float4*)sV[g];
      float4 V0 = vb[0], V1 = vb[1], V2 = vb[2], V3 = vb[3], V4 = vb[4], V5 = vb[5];
      float b0v, b1v, b2v;
      int i0, i1, i2;
#define ARGSTEP(BV, BI, VAL, IDX)          \
  {                                        \
    float x_ = (VAL) + Tc[IDX];            \
    if (x_ > BV) { BV = x_; BI = (IDX); }  \
  }
      b0v = V0.x + Tc[0]; i0 = 0;
      b1v = V0.y + Tc[1]; i1 = 1;
      b2v = V0.z + Tc[2]; i2 = 2;
      ARGSTEP(b0v, i0, V0.w, 3);  ARGSTEP(b1v, i1, V1.x, 4);  ARGSTEP(b2v, i2, V1.y, 5);
      ARGSTEP(b0v, i0, V1.z, 6);  ARGSTEP(b1v, i1, V1.w, 7);  ARGSTEP(b2v, i2, V2.x, 8);
      ARGSTEP(b0v, i0, V2.y, 9);  ARGSTEP(b1v, i1, V2.z, 10); ARGSTEP(b2v, i2, V2.w, 11);
      ARGSTEP(b0v, i0, V3.x, 12); ARGSTEP(b1v, i1, V3.y, 13); ARGSTEP(b2v, i2, V3.z, 14);
      ARGSTEP(b0v, i0, V3.w, 15); ARGSTEP(b1v, i1, V4.x, 16); ARGSTEP(b2v, i2, V4.y, 17);
      ARGSTEP(b0v, i0, V4.z, 18); ARGSTEP(b1v, i1, V4.w, 19); ARGSTEP(b2v, i2, V5.x, 20);
#undef ARGSTEP
      // merge with first-index tie-break (matches jnp.argmax)
      float best = b0v;
      int bi = i0;
      if (b1v > best || (b1v == best && i1 < bi)) { best = b1v; bi = i1; }
      if (b2v > best || (b2v == best && i2 < bi)) { best = b2v; bi = i2; }
      float ns = best + e;
      sc = (act && mk) ? ns : sc;
      bp[g][t][j] = (unsigned char)(mk ? bi : j);
    }
    float fsv = act ? (sc + ev[jj]) : -3.0e38f;
    int idx = j;
#pragma unroll
    for (int d = 16; d >= 1; d >>= 1) {
      float ov = __shfl_xor(fsv, d);
      int oi = __shfl_xor(idx, d);
      bool take = (ov > fsv) || (ov == fsv && oi < idx);
      fsv = take ? ov : fsv;
      idx = take ? oi : idx;
    }
    __syncthreads();
    if (j == 0) {
      int tag = idx;
      sTag[g][SS - 1] = (unsigned char)tag;
      for (int t = SS - 1; t >= 1; --t) {
        tag = bp[g][t][tag];
        sTag[g][t - 1] = (unsigned char)tag;
      }
    }
    __syncthreads();
    // coalesced copy-out: pred = where(mask, tags, 0) as float
    for (int i = lane; i < 2 * SS; i += 64) {
      pred[(size_t)b0 * SS + i] = (float)(sM[i] ? (int)sTag[i >> 9][i & (SS - 1)] : 0);
    }
  }
}

// ---------------- Kernel 3: numerator + loss, one block per batch ----------------
__global__ __launch_bounds__(64, 1) void k_loss(const float* __restrict__ emis,
                                                const int* __restrict__ mask,
                                                const int* __restrict__ labels,
                                                const float* __restrict__ trans,
                                                const float* __restrict__ sv,
                                                const float* __restrict__ ev,
                                                const float* __restrict__ logZ,
                                                float* __restrict__ outv) {
  const int b = blockIdx.x;
  const int lane = threadIdx.x;
  float p = 0.f;
  int cnt = 0;
  for (int t = lane; t < SS; t += 64) {
    cnt += mask[b * SS + t] ? 1 : 0;
    if (t >= 1) {
      const int lp = labels[b * SS + t - 1];
      const int lc = labels[b * SS + t];
      const float mk = (float)mask[b * SS + t];
      p += mk * (trans[lp * TT + lc] + emis[((size_t)b * SS + t) * TT + lc]);
    }
  }
  p = wave_sum(p);
#pragma unroll
  for (int d = 32; d >= 1; d >>= 1) cnt += __shfl_xor(cnt, d);
  if (lane == 0) {
    const int l0 = labels[b * SS];
    float numer = p + sv[l0] + emis[(size_t)b * SS * TT + l0];
    numer += ev[labels[b * SS + cnt - 1]];
    atomicAdd(outv, logZ[b] - numer);  // loss = sum_b (logZ - numerator)
  }
}

extern "C" void kernel_launch(void* const* d_in, const int* in_sizes, int n_in,
                              void* d_out, int out_size, void* d_ws, size_t ws_size,
                              hipStream_t stream) {
  const float* hs = (const float*)d_in[0];
  const int* msk = (const int*)d_in[1];
  const int* lab = (const int*)d_in[2];
  const float* W = (const float*)d_in[3];
  const float* bias = (const float*)d_in[4];
  const float* trans = (const float*)d_in[5];
  const float* sv = (const float*)d_in[6];
  const float* ev = (const float*)d_in[7];
  float* out = (float*)d_out;

  float* emis = (float*)d_ws;                 // 64*512*21 floats
  float* logZ = emis + (size_t)BB * SS * TT;  // 64 floats

  hipMemsetAsync(d_out, 0, 4, stream);  // zero the loss accumulator
  k_emis<<<1024, 256, 0, stream>>>(hs, W, bias, emis);
  k_scan<<<64, 64, 0, stream>>>(emis, msk, trans, sv, ev, logZ, out + 1);
  k_loss<<<64, 64, 0, stream>>>(emis, msk, lab, trans, sv, ev, logZ, out);
}

// Round 2
// 526.299 us; speedup vs baseline: 1.3894x; 1.3894x over previous
//
#include <hip/hip_runtime.h>
#include <math.h>
#include <stdint.h>

#define BB 64
#define SS 512
#define HH 1024
#define TT 21

// DPP-based partial reduce within row of 16, then cross-row shuffles.
template <int CTRL>
__device__ __forceinline__ float dpp_add(float v) {
  int t = __builtin_amdgcn_update_dpp(0, __float_as_int(v), CTRL, 0xF, 0xF, true);
  return v + __int_as_float(t);
}
__device__ __forceinline__ float wave_sum(float v) {
  v = dpp_add<0x121>(v);  // row_ror:1
  v = dpp_add<0x122>(v);  // row_ror:2
  v = dpp_add<0x124>(v);  // row_ror:4
  v = dpp_add<0x128>(v);  // row_ror:8
  v += __shfl_xor(v, 16);
  v += __shfl_xor(v, 32);
  return v;
}

#define DOT4(A, H, WV)    \
  A = fmaf(H.x, WV.x, A); \
  A = fmaf(H.y, WV.y, A); \
  A = fmaf(H.z, WV.z, A); \
  A = fmaf(H.w, WV.w, A)

// ---------------- Kernel 1: emissions = hs @ W^T + bias ----------------
// Round-2 fix: round-1's 21-acc/thread version spilled to scratch
// (WRITE_SIZE 510 MB vs 2.75 MB ideal). Split the 21 outputs across 3
// thread groups of 7: thread = (row, t-group, K-eighth). 7 acc + 8 h +
// a few w quads ~= 35 VGPRs -> no spill. Same coalescing (q-lanes cover
// 128B segments; t-group address duplicates merge in the coalescer).
// Emission arithmetic is bit-identical to the round-1 ordering.
__global__ __launch_bounds__(192) void k_emis(const float* __restrict__ hs,
                                              const float* __restrict__ W,
                                              const float* __restrict__ bias,
                                              float* __restrict__ emis) {
  __shared__ float part[192 * 7];  // 5376 B
  const int tid = threadIdx.x;
  const int q = tid & 7;       // K-phase 0..7 (covers k4 = 8*i + q)
  const int tmp = tid >> 3;    // 0..23
  const int tg = tmp % 3;      // t-group (7 tags each)
  const int r = tmp / 3;       // row-in-block 0..7
  const size_t row = (size_t)blockIdx.x * 8 + r;
  const float4* hp = (const float4*)(hs + row * HH);
  const float* wb0 = W + (size_t)(tg * 7) * HH + q * 4;

  float acc[7] = {0.f, 0.f, 0.f, 0.f, 0.f, 0.f, 0.f};
  float4 h = hp[q];  // i = 0 prefetched
  for (int i = 0; i < 32; ++i) {
    const float4 hc = h;
    if (i < 31) h = hp[(i + 1) * 8 + q];  // prefetch next chunk of this row
    const float* wb = wb0 + (size_t)i * 32;
#pragma unroll
    for (int lt = 0; lt < 7; ++lt) {
      const float4 w = *(const float4*)(wb + (size_t)lt * HH);
      DOT4(acc[lt], hc, w);
    }
  }
#pragma unroll
  for (int lt = 0; lt < 7; ++lt) part[tid * 7 + lt] = acc[lt];
  __syncthreads();

  // combine 8 K-phases; 168 contiguous outputs per block -> coalesced
  if (tid < 8 * TT) {
    const int rr = tid / TT;
    const int t = tid - rr * TT;
    const int tg2 = t / 7;
    const int lt2 = t - tg2 * 7;
    const float* pp = part + ((rr * 3 + tg2) * 8) * 7 + lt2;
    float s = ((pp[0] + pp[7]) + (pp[14] + pp[21])) +
              ((pp[28] + pp[35]) + (pp[42] + pp[49]));
    emis[(size_t)blockIdx.x * (8 * TT) + tid] = s + bias[t];
  }
}

// ---------------- Kernel 2: CRF forward scan + Viterbi ----------------
// Round-2 restructure: one batch per wave (128 blocks). The per-step
// 21-value broadcast is done with v_readlane into SGPRs -- no LDS
// write/read, no barrier in the loop. v_fma with one SGPR operand is
// legal, so the q/argmax chains consume the scalars directly. All
// arithmetic is order-identical to the verified kernel (the extra d=32
// reduce step only adds exact zeros).
#define RLF(V, K) __int_as_float(__builtin_amdgcn_readlane(__float_as_int(V), K))

__global__ __launch_bounds__(64, 1) void k_scan(const float* __restrict__ emis,
                                                const int* __restrict__ mask,
                                                const float* __restrict__ trans,
                                                const float* __restrict__ sv,
                                                const float* __restrict__ ev,
                                                float* __restrict__ logZ,
                                                float* __restrict__ pred) {
  __shared__ float sE[SS * TT];         // 42 KiB
  __shared__ int sM[SS];                // 2 KiB
  __shared__ unsigned char bp[SS][32];  // 16 KiB (viterbi only)
  __shared__ unsigned char sTag[SS];    // 0.5 KiB (viterbi only)
  const int lane = threadIdx.x;
  const int j = lane;
  const bool act = (j < TT);
  const int jj = act ? j : 0;
  const int b = blockIdx.x & 63;

  // ---- stage emissions + mask for this batch ----
  {
    const float4* src = (const float4*)(emis + (size_t)b * SS * TT);
    float4* dst = (float4*)sE;
    for (int i = lane; i < SS * TT / 4; i += 64) dst[i] = src[i];
    const int* msrc = mask + b * SS;
    for (int i = lane; i < SS; i += 64) sM[i] = msrc[i];
  }
  __syncthreads();

  if (blockIdx.x < 64) {
    // ---- CRF logsumexp scan (exp domain, v = exp(alpha - C)) ----
    float E[TT];
#pragma unroll
    for (int i = 0; i < TT; ++i) E[i] = __expf(trans[i * TT + jj]);
    float v = act ? __expf(sv[jj] + sE[jj]) : 0.f;
    float C = 0.f;
    float ge_nx = __expf(sE[TT + jj]);
    int mk_nx = sM[1];
    for (int t = 1; t < SS; ++t) {
      const float ge = ge_nx;
      const int mk = mk_nx;
      const int tn = (t + 1 < SS) ? (t + 1) : (SS - 1);
      ge_nx = __expf(sE[tn * TT + jj]);
      mk_nx = sM[tn];
      // broadcast all 21 v's via readlane (uniform SGPRs)
      const float v0 = RLF(v, 0), v1 = RLF(v, 1), v2 = RLF(v, 2);
      const float v3 = RLF(v, 3), v4 = RLF(v, 4), v5 = RLF(v, 5);
      const float v6 = RLF(v, 6), v7 = RLF(v, 7), v8 = RLF(v, 8);
      const float v9 = RLF(v, 9), v10 = RLF(v, 10), v11 = RLF(v, 11);
      const float v12 = RLF(v, 12), v13 = RLF(v, 13), v14 = RLF(v, 14);
      const float v15 = RLF(v, 15), v16 = RLF(v, 16), v17 = RLF(v, 17);
      const float v18 = RLF(v, 18), v19 = RLF(v, 19), v20 = RLF(v, 20);
      float scale = 1.0f;
      if ((t & 7) == 0) {
        float m = fmaxf(fmaxf(fmaxf(v0, v1), fmaxf(v2, v3)),
                        fmaxf(fmaxf(v4, v5), fmaxf(v6, v7)));
        m = fmaxf(m, fmaxf(fmaxf(v8, v9), fmaxf(v10, v11)));
        m = fmaxf(m, fmaxf(fmaxf(v12, v13), fmaxf(v14, v15)));
        m = fmaxf(m, fmaxf(fmaxf(v16, v17), fmaxf(v18, v19)));
        m = fmaxf(m, v20);
        int ex = (int)((__float_as_uint(m) >> 23) & 255u) - 127;
        scale = __uint_as_float((unsigned)(127 - ex) << 23);  // 2^-ex exact
        C += (float)ex * 0.6931471805599453f;
        v *= scale;  // keep masked lanes consistent with C
      }
      // q chains: identical summation order to the verified kernel
      float q0 = v0 * E[0], q1 = v1 * E[1], q2 = v2 * E[2];
      q0 = fmaf(v3, E[3], q0);   q1 = fmaf(v4, E[4], q1);   q2 = fmaf(v5, E[5], q2);
      q0 = fmaf(v6, E[6], q0);   q1 = fmaf(v7, E[7], q1);   q2 = fmaf(v8, E[8], q2);
      q0 = fmaf(v9, E[9], q0);   q1 = fmaf(v10, E[10], q1); q2 = fmaf(v11, E[11], q2);
      q0 = fmaf(v12, E[12], q0); q1 = fmaf(v13, E[13], q1); q2 = fmaf(v14, E[14], q2);
      q0 = fmaf(v15, E[15], q0); q1 = fmaf(v16, E[16], q1); q2 = fmaf(v17, E[17], q2);
      q0 = fmaf(v18, E[18], q0); q1 = fmaf(v19, E[19], q1); q2 = fmaf(v20, E[20], q2);
      float vn = ((q0 + q1 + q2) * scale) * ge;
      v = (act && mk) ? vn : v;
    }
    float wv = act ? v * __expf(ev[jj]) : 0.f;
#pragma unroll
    for (int d = 32; d >= 1; d >>= 1) wv += __shfl_xor(wv, d);
    if (lane == 0) logZ[b] = C + __logf(wv);
  } else {
    // ---- Viterbi: readlane broadcast + 3 argmax chains + tie-safe merge ----
    float Tc[TT];
#pragma unroll
    for (int i = 0; i < TT; ++i) Tc[i] = trans[i * TT + jj];
    float sc = act ? (sv[jj] + sE[jj]) : -3.0e38f;
    float e_nx = sE[TT + jj];
    int mk_nx = sM[1];
    for (int t = 1; t < SS; ++t) {
      const float e = e_nx;
      const int mk = mk_nx;
      const int tn = (t + 1 < SS) ? (t + 1) : (SS - 1);
      e_nx = sE[tn * TT + jj];
      mk_nx = sM[tn];
      const float s0 = RLF(sc, 0), s1 = RLF(sc, 1), s2 = RLF(sc, 2);
      const float s3 = RLF(sc, 3), s4 = RLF(sc, 4), s5 = RLF(sc, 5);
      const float s6 = RLF(sc, 6), s7 = RLF(sc, 7), s8 = RLF(sc, 8);
      const float s9 = RLF(sc, 9), s10 = RLF(sc, 10), s11 = RLF(sc, 11);
      const float s12 = RLF(sc, 12), s13 = RLF(sc, 13), s14 = RLF(sc, 14);
      const float s15 = RLF(sc, 15), s16 = RLF(sc, 16), s17 = RLF(sc, 17);
      const float s18 = RLF(sc, 18), s19 = RLF(sc, 19), s20 = RLF(sc, 20);
      float b0v, b1v, b2v;
      int i0, i1, i2;
#define ARGSTEP(BV, BI, VAL, IDX)          \
  {                                        \
    float x_ = (VAL) + Tc[IDX];            \
    if (x_ > BV) { BV = x_; BI = (IDX); }  \
  }
      b0v = s0 + Tc[0]; i0 = 0;
      b1v = s1 + Tc[1]; i1 = 1;
      b2v = s2 + Tc[2]; i2 = 2;
      ARGSTEP(b0v, i0, s3, 3);   ARGSTEP(b1v, i1, s4, 4);   ARGSTEP(b2v, i2, s5, 5);
      ARGSTEP(b0v, i0, s6, 6);   ARGSTEP(b1v, i1, s7, 7);   ARGSTEP(b2v, i2, s8, 8);
      ARGSTEP(b0v, i0, s9, 9);   ARGSTEP(b1v, i1, s10, 10); ARGSTEP(b2v, i2, s11, 11);
      ARGSTEP(b0v, i0, s12, 12); ARGSTEP(b1v, i1, s13, 13); ARGSTEP(b2v, i2, s14, 14);
      ARGSTEP(b0v, i0, s15, 15); ARGSTEP(b1v, i1, s16, 16); ARGSTEP(b2v, i2, s17, 17);
      ARGSTEP(b0v, i0, s18, 18); ARGSTEP(b1v, i1, s19, 19); ARGSTEP(b2v, i2, s20, 20);
#undef ARGSTEP
      // merge with first-index tie-break (matches jnp.argmax)
      float best = b0v;
      int bi = i0;
      if (b1v > best || (b1v == best && i1 < bi)) { best = b1v; bi = i1; }
      if (b2v > best || (b2v == best && i2 < bi)) { best = b2v; bi = i2; }
      float ns = best + e;
      sc = (act && mk) ? ns : sc;
      if (act) bp[t][j] = (unsigned char)(mk ? bi : j);
    }
    float fsv = act ? (sc + ev[jj]) : -3.0e38f;
    int idx = j;
#pragma unroll
    for (int d = 32; d >= 1; d >>= 1) {
      float ov = __shfl_xor(fsv, d);
      int oi = __shfl_xor(idx, d);
      bool take = (ov > fsv) || (ov == fsv && oi < idx);
      fsv = take ? ov : fsv;
      idx = take ? oi : idx;
    }
    __syncthreads();
    if (lane == 0) {
      int tag = idx;
      sTag[SS - 1] = (unsigned char)tag;
      for (int t = SS - 1; t >= 1; --t) {
        tag = bp[t][tag];
        sTag[t - 1] = (unsigned char)tag;
      }
    }
    __syncthreads();
    // coalesced copy-out: pred = where(mask, tags, 0) as float
    for (int i = lane; i < SS; i += 64) {
      pred[(size_t)b * SS + i] = (float)(sM[i] ? (int)sTag[i] : 0);
    }
  }
}

// ---------------- Kernel 3: numerator + loss, one block per batch ----------------
__global__ __launch_bounds__(64, 1) void k_loss(const float* __restrict__ emis,
                                                const int* __restrict__ mask,
                                                const int* __restrict__ labels,
                                                const float* __restrict__ trans,
                                                const float* __restrict__ sv,
                                                const float* __restrict__ ev,
                                                const float* __restrict__ logZ,
                                                float* __restrict__ outv) {
  const int b = blockIdx.x;
  const int lane = threadIdx.x;
  float p = 0.f;
  int cnt = 0;
  for (int t = lane; t < SS; t += 64) {
    cnt += mask[b * SS + t] ? 1 : 0;
    if (t >= 1) {
      const int lp = labels[b * SS + t - 1];
      const int lc = labels[b * SS + t];
      const float mk = (float)mask[b * SS + t];
      p += mk * (trans[lp * TT + lc] + emis[((size_t)b * SS + t) * TT + lc]);
    }
  }
  p = wave_sum(p);
#pragma unroll
  for (int d = 32; d >= 1; d >>= 1) cnt += __shfl_xor(cnt, d);
  if (lane == 0) {
    const int l0 = labels[b * SS];
    float numer = p + sv[l0] + emis[(size_t)b * SS * TT + l0];
    numer += ev[labels[b * SS + cnt - 1]];
    atomicAdd(outv, logZ[b] - numer);  // loss = sum_b (logZ - numerator)
  }
}

extern "C" void kernel_launch(void* const* d_in, const int* in_sizes, int n_in,
                              void* d_out, int out_size, void* d_ws, size_t ws_size,
                              hipStream_t stream) {
  const float* hs = (const float*)d_in[0];
  const int* msk = (const int*)d_in[1];
  const int* lab = (const int*)d_in[2];
  const float* W = (const float*)d_in[3];
  const float* bias = (const float*)d_in[4];
  const float* trans = (const float*)d_in[5];
  const float* sv = (const float*)d_in[6];
  const float* ev = (const float*)d_in[7];
  float* out = (float*)d_out;

  float* emis = (float*)d_ws;                 // 64*512*21 floats
  float* logZ = emis + (size_t)BB * SS * TT;  // 64 floats

  hipMemsetAsync(d_out, 0, 4, stream);  // zero the loss accumulator
  k_emis<<<4096, 192, 0, stream>>>(hs, W, bias, emis);
  k_scan<<<128, 64, 0, stream>>>(emis, msk, trans, sv, ev, logZ, out + 1);
  k_loss<<<64, 64, 0, stream>>>(emis, msk, lab, trans, sv, ev, logZ, out);
}

// Round 3
// 432.108 us; speedup vs baseline: 1.6923x; 1.2180x over previous
//
#include <hip/hip_runtime.h>
#include <math.h>
#include <stdint.h>

#define BB 64
#define SS 512
#define HH 1024
#define TT 21

// DPP-based partial reduce within row of 16, then cross-row shuffles.
template <int CTRL>
__device__ __forceinline__ float dpp_add(float v) {
  int t = __builtin_amdgcn_update_dpp(0, __float_as_int(v), CTRL, 0xF, 0xF, true);
  return v + __int_as_float(t);
}
__device__ __forceinline__ float wave_sum(float v) {
  v = dpp_add<0x121>(v);  // row_ror:1
  v = dpp_add<0x122>(v);  // row_ror:2
  v = dpp_add<0x124>(v);  // row_ror:4
  v = dpp_add<0x128>(v);  // row_ror:8
  v += __shfl_xor(v, 16);
  v += __shfl_xor(v, 32);
  return v;
}

#define DOT4(A, H, WV)    \
  A = fmaf(H.x, WV.x, A); \
  A = fmaf(H.y, WV.y, A); \
  A = fmaf(H.z, WV.z, A); \
  A = fmaf(H.w, WV.w, A)

// ---------------- Kernel 1: emissions = hs @ W^T + bias ----------------
// Round-3: 2-row register tiling on top of the round-2 structure.
// thread = (row-pair, t-group of 7, K-eighth): 14 acc regs, W loads
// amortized over 2 rows (halves W L2 traffic, doubles FMA:VMEM ratio).
// launch_bounds(192,4) caps VGPR<=128 to forbid the round-1 spill mode.
// Per-accumulator FMA order identical to round-2 (bit-exact emissions).
__global__ __launch_bounds__(192, 4) void k_emis(const float* __restrict__ hs,
                                                 const float* __restrict__ W,
                                                 const float* __restrict__ bias,
                                                 float* __restrict__ emis) {
  __shared__ float part[192 * 14];  // 10752 B
  const int tid = threadIdx.x;
  const int q = tid & 7;     // K-phase 0..7 (covers k4 = 8*i + q)
  const int tmp = tid >> 3;  // 0..23
  const int tg = tmp % 3;    // t-group (7 tags each)
  const int rp = tmp / 3;    // row-pair 0..7 -> rows 2rp, 2rp+1
  const size_t row0 = (size_t)blockIdx.x * 16 + rp * 2;
  const float4* hp0 = (const float4*)(hs + row0 * HH);
  const float4* hp1 = (const float4*)(hs + (row0 + 1) * HH);
  const float* wb0 = W + (size_t)(tg * 7) * HH + q * 4;

  float a0[7] = {0.f, 0.f, 0.f, 0.f, 0.f, 0.f, 0.f};
  float a1[7] = {0.f, 0.f, 0.f, 0.f, 0.f, 0.f, 0.f};
  float4 h0 = hp0[q], h1 = hp1[q];  // i = 0 prefetched
#pragma unroll 2
  for (int i = 0; i < 32; ++i) {
    const float4 hc0 = h0, hc1 = h1;
    if (i < 31) {
      h0 = hp0[(i + 1) * 8 + q];
      h1 = hp1[(i + 1) * 8 + q];
    }
    const float* wb = wb0 + (size_t)i * 32;
#pragma unroll
    for (int lt = 0; lt < 7; ++lt) {
      const float4 w = *(const float4*)(wb + (size_t)lt * HH);
      DOT4(a0[lt], hc0, w);
      DOT4(a1[lt], hc1, w);
    }
  }
#pragma unroll
  for (int lt = 0; lt < 7; ++lt) {
    part[tid * 14 + lt] = a0[lt];
    part[tid * 14 + 7 + lt] = a1[lt];
  }
  __syncthreads();

  // combine 8 K-phases; 336 contiguous outputs per block -> coalesced
  for (int o = tid; o < 16 * TT; o += 192) {
    const int rr = o / TT;
    const int t = o - rr * TT;
    const int tg2 = t / 7;
    const int lt2 = t - tg2 * 7;
    const float* pp = part + (((rr >> 1) * 3 + tg2) * 8) * 14 + (rr & 1) * 7 + lt2;
    // same q-ascending tree as round-2 (q stride is now 14 floats)
    float s = ((pp[0] + pp[14]) + (pp[28] + pp[42])) +
              ((pp[56] + pp[70]) + (pp[84] + pp[98]));
    emis[(size_t)blockIdx.x * (16 * TT) + o] = s + bias[t];
  }
}

// ---------------- Kernel 2: CRF forward scan + Viterbi ----------------
// Round-3: all broadcast variants measured ~equal -> the loop is latency-
// bound on per-iter LDS reads + waits, not on the readlane chain. Remove
// ALL per-iteration memory ops: emissions stream straight from global in
// 8-step register chunks (prefetched one chunk ahead), masks via rolling
// int4 quads (compile-time component select), exp per-chunk. Renorm's
// (t&7)==0 is exactly the chunk boundary -> compile-time p==7. Arithmetic
// order identical to the verified kernel (bit-exact).
#define RLF(V, K) __int_as_float(__builtin_amdgcn_readlane(__float_as_int(V), K))

__global__ __launch_bounds__(64, 1) void k_scan(const float* __restrict__ emis,
                                                const int* __restrict__ mask,
                                                const float* __restrict__ trans,
                                                const float* __restrict__ sv,
                                                const float* __restrict__ ev,
                                                float* __restrict__ logZ,
                                                float* __restrict__ pred) {
  __shared__ unsigned char bp[SS][32];  // 16 KiB (viterbi only)
  __shared__ unsigned char sTag[SS];    // 0.5 KiB (viterbi only)
  const int lane = threadIdx.x;
  const int j = lane;
  const bool act = (j < TT);
  const int jj = act ? j : 0;
  const int b = blockIdx.x & 63;
  const float* eb = emis + (size_t)b * SS * TT + jj;  // lane's emission column
  const int4* mq = (const int4*)(mask + b * SS);      // 128 aligned quads

  if (blockIdx.x < 64) {
    // ---- CRF logsumexp scan (exp domain, v = exp(alpha - C)) ----
    float E[TT];
#pragma unroll
    for (int i = 0; i < TT; ++i) E[i] = __expf(trans[i * TT + jj]);
    float v = act ? __expf(sv[jj] + eb[0]) : 0.f;
    float C = 0.f;
    float pre[8], cur[8];
#pragma unroll
    for (int k = 0; k < 8; ++k) pre[k] = eb[(size_t)(1 + k) * TT];  // chunk 0
    int4 qA = mq[0];
    for (int c = 0; c < 64; ++c) {
      const int base = c * 8;
      const int4 qB = mq[2 * c + 1];
      const int4 qC = mq[(2 * c + 2 < 128) ? (2 * c + 2) : 127];
      float ge[8];
#pragma unroll
      for (int k = 0; k < 8; ++k) cur[k] = pre[k];
#pragma unroll
      for (int k = 0; k < 8; ++k) ge[k] = __expf(cur[k]);
      if (c < 63) {
#pragma unroll
        for (int k = 0; k < 8; ++k) {
          int tl = base + 9 + k;
          tl = (tl < SS) ? tl : (SS - 1);
          pre[k] = eb[(size_t)tl * TT];
        }
      }
      const int mks[8] = {qA.y, qA.z, qA.w, qB.x, qB.y, qB.z, qB.w, qC.x};
#pragma unroll
      for (int p = 0; p < 8; ++p) {
        const int t = base + 1 + p;
        if (t >= SS) break;  // only last chunk, p == 7
        const int mk = mks[p];
        const float ge_t = ge[p];
        const float v0 = RLF(v, 0), v1 = RLF(v, 1), v2 = RLF(v, 2);
        const float v3 = RLF(v, 3), v4 = RLF(v, 4), v5 = RLF(v, 5);
        const float v6 = RLF(v, 6), v7 = RLF(v, 7), v8 = RLF(v, 8);
        const float v9 = RLF(v, 9), v10 = RLF(v, 10), v11 = RLF(v, 11);
        const float v12 = RLF(v, 12), v13 = RLF(v, 13), v14 = RLF(v, 14);
        const float v15 = RLF(v, 15), v16 = RLF(v, 16), v17 = RLF(v, 17);
        const float v18 = RLF(v, 18), v19 = RLF(v, 19), v20 = RLF(v, 20);
        float scale = 1.0f;
        if (p == 7) {  // t = 8(c+1): exactly the old (t&7)==0 sites
          float m = fmaxf(fmaxf(fmaxf(v0, v1), fmaxf(v2, v3)),
                          fmaxf(fmaxf(v4, v5), fmaxf(v6, v7)));
          m = fmaxf(m, fmaxf(fmaxf(v8, v9), fmaxf(v10, v11)));
          m = fmaxf(m, fmaxf(fmaxf(v12, v13), fmaxf(v14, v15)));
          m = fmaxf(m, fmaxf(fmaxf(v16, v17), fmaxf(v18, v19)));
          m = fmaxf(m, v20);
          int ex = (int)((__float_as_uint(m) >> 23) & 255u) - 127;
          scale = __uint_as_float((unsigned)(127 - ex) << 23);  // 2^-ex exact
          C += (float)ex * 0.6931471805599453f;
          v *= scale;  // keep masked lanes consistent with C
        }
        // q chains: identical summation order to the verified kernel
        float q0 = v0 * E[0], q1 = v1 * E[1], q2 = v2 * E[2];
        q0 = fmaf(v3, E[3], q0);   q1 = fmaf(v4, E[4], q1);   q2 = fmaf(v5, E[5], q2);
        q0 = fmaf(v6, E[6], q0);   q1 = fmaf(v7, E[7], q1);   q2 = fmaf(v8, E[8], q2);
        q0 = fmaf(v9, E[9], q0);   q1 = fmaf(v10, E[10], q1); q2 = fmaf(v11, E[11], q2);
        q0 = fmaf(v12, E[12], q0); q1 = fmaf(v13, E[13], q1); q2 = fmaf(v14, E[14], q2);
        q0 = fmaf(v15, E[15], q0); q1 = fmaf(v16, E[16], q1); q2 = fmaf(v17, E[17], q2);
        q0 = fmaf(v18, E[18], q0); q1 = fmaf(v19, E[19], q1); q2 = fmaf(v20, E[20], q2);
        float vn = ((q0 + q1 + q2) * scale) * ge_t;
        v = (act && mk) ? vn : v;
      }
      qA = qC;
    }
    float wv = act ? v * __expf(ev[jj]) : 0.f;
#pragma unroll
    for (int d = 32; d >= 1; d >>= 1) wv += __shfl_xor(wv, d);
    if (lane == 0) logZ[b] = C + __logf(wv);
  } else {
    // ---- Viterbi: same streaming structure, argmax chains ----
    float Tc[TT];
#pragma unroll
    for (int i = 0; i < TT; ++i) Tc[i] = trans[i * TT + jj];
    float sc = act ? (sv[jj] + eb[0]) : -3.0e38f;
    float pre[8], cur[8];
#pragma unroll
    for (int k = 0; k < 8; ++k) pre[k] = eb[(size_t)(1 + k) * TT];
    int4 qA = mq[0];
    for (int c = 0; c < 64; ++c) {
      const int base = c * 8;
      const int4 qB = mq[2 * c + 1];
      const int4 qC = mq[(2 * c + 2 < 128) ? (2 * c + 2) : 127];
#pragma unroll
      for (int k = 0; k < 8; ++k) cur[k] = pre[k];
      if (c < 63) {
#pragma unroll
        for (int k = 0; k < 8; ++k) {
          int tl = base + 9 + k;
          tl = (tl < SS) ? tl : (SS - 1);
          pre[k] = eb[(size_t)tl * TT];
        }
      }
      const int mks[8] = {qA.y, qA.z, qA.w, qB.x, qB.y, qB.z, qB.w, qC.x};
#pragma unroll
      for (int p = 0; p < 8; ++p) {
        const int t = base + 1 + p;
        if (t >= SS) break;
        const int mk = mks[p];
        const float e = cur[p];
        const float s0 = RLF(sc, 0), s1 = RLF(sc, 1), s2 = RLF(sc, 2);
        const float s3 = RLF(sc, 3), s4 = RLF(sc, 4), s5 = RLF(sc, 5);
        const float s6 = RLF(sc, 6), s7 = RLF(sc, 7), s8 = RLF(sc, 8);
        const float s9 = RLF(sc, 9), s10 = RLF(sc, 10), s11 = RLF(sc, 11);
        const float s12 = RLF(sc, 12), s13 = RLF(sc, 13), s14 = RLF(sc, 14);
        const float s15 = RLF(sc, 15), s16 = RLF(sc, 16), s17 = RLF(sc, 17);
        const float s18 = RLF(sc, 18), s19 = RLF(sc, 19), s20 = RLF(sc, 20);
        float b0v, b1v, b2v;
        int i0, i1, i2;
#define ARGSTEP(BV, BI, VAL, IDX)          \
  {                                        \
    float x_ = (VAL) + Tc[IDX];            \
    if (x_ > BV) { BV = x_; BI = (IDX); }  \
  }
        b0v = s0 + Tc[0]; i0 = 0;
        b1v = s1 + Tc[1]; i1 = 1;
        b2v = s2 + Tc[2]; i2 = 2;
        ARGSTEP(b0v, i0, s3, 3);   ARGSTEP(b1v, i1, s4, 4);   ARGSTEP(b2v, i2, s5, 5);
        ARGSTEP(b0v, i0, s6, 6);   ARGSTEP(b1v, i1, s7, 7);   ARGSTEP(b2v, i2, s8, 8);
        ARGSTEP(b0v, i0, s9, 9);   ARGSTEP(b1v, i1, s10, 10); ARGSTEP(b2v, i2, s11, 11);
        ARGSTEP(b0v, i0, s12, 12); ARGSTEP(b1v, i1, s13, 13); ARGSTEP(b2v, i2, s14, 14);
        ARGSTEP(b0v, i0, s15, 15); ARGSTEP(b1v, i1, s16, 16); ARGSTEP(b2v, i2, s17, 17);
        ARGSTEP(b0v, i0, s18, 18); ARGSTEP(b1v, i1, s19, 19); ARGSTEP(b2v, i2, s20, 20);
#undef ARGSTEP
        // merge with first-index tie-break (matches jnp.argmax)
        float best = b0v;
        int bi = i0;
        if (b1v > best || (b1v == best && i1 < bi)) { best = b1v; bi = i1; }
        if (b2v > best || (b2v == best && i2 < bi)) { best = b2v; bi = i2; }
        float ns = best + e;
        sc = (act && mk) ? ns : sc;
        if (act) bp[t][j] = (unsigned char)(mk ? bi : j);
      }
      qA = qC;
    }
    float fsv = act ? (sc + ev[jj]) : -3.0e38f;
    int idx = j;
#pragma unroll
    for (int d = 32; d >= 1; d >>= 1) {
      float ov = __shfl_xor(fsv, d);
      int oi = __shfl_xor(idx, d);
      bool take = (ov > fsv) || (ov == fsv && oi < idx);
      fsv = take ? ov : fsv;
      idx = take ? oi : idx;
    }
    __syncthreads();
    if (lane == 0) {
      int tag = idx;
      sTag[SS - 1] = (unsigned char)tag;
      for (int t = SS - 1; t >= 1; --t) {
        tag = bp[t][tag];
        sTag[t - 1] = (unsigned char)tag;
      }
    }
    __syncthreads();
    // coalesced copy-out: pred = where(mask, tags, 0) as float
    for (int i = lane; i < SS; i += 64) {
      pred[(size_t)b * SS + i] = (float)(mask[b * SS + i] ? (int)sTag[i] : 0);
    }
  }
}

// ---------------- Kernel 3: numerator + loss, one block per batch ----------------
__global__ __launch_bounds__(64, 1) void k_loss(const float* __restrict__ emis,
                                                const int* __restrict__ mask,
                                                const int* __restrict__ labels,
                                                const float* __restrict__ trans,
                                                const float* __restrict__ sv,
                                                const float* __restrict__ ev,
                                                const float* __restrict__ logZ,
                                                float* __restrict__ outv) {
  const int b = blockIdx.x;
  const int lane = threadIdx.x;
  float p = 0.f;
  int cnt = 0;
  for (int t = lane; t < SS; t += 64) {
    cnt += mask[b * SS + t] ? 1 : 0;
    if (t >= 1) {
      const int lp = labels[b * SS + t - 1];
      const int lc = labels[b * SS + t];
      const float mk = (float)mask[b * SS + t];
      p += mk * (trans[lp * TT + lc] + emis[((size_t)b * SS + t) * TT + lc]);
    }
  }
  p = wave_sum(p);
#pragma unroll
  for (int d = 32; d >= 1; d >>= 1) cnt += __shfl_xor(cnt, d);
  if (lane == 0) {
    const int l0 = labels[b * SS];
    float numer = p + sv[l0] + emis[(size_t)b * SS * TT + l0];
    numer += ev[labels[b * SS + cnt - 1]];
    atomicAdd(outv, logZ[b] - numer);  // loss = sum_b (logZ - numerator)
  }
}

extern "C" void kernel_launch(void* const* d_in, const int* in_sizes, int n_in,
                              void* d_out, int out_size, void* d_ws, size_t ws_size,
                              hipStream_t stream) {
  const float* hs = (const float*)d_in[0];
  const int* msk = (const int*)d_in[1];
  const int* lab = (const int*)d_in[2];
  const float* W = (const float*)d_in[3];
  const float* bias = (const float*)d_in[4];
  const float* trans = (const float*)d_in[5];
  const float* sv = (const float*)d_in[6];
  const float* ev = (const float*)d_in[7];
  float* out = (float*)d_out;

  float* emis = (float*)d_ws;                 // 64*512*21 floats
  float* logZ = emis + (size_t)BB * SS * TT;  // 64 floats

  hipMemsetAsync(d_out, 0, 4, stream);  // zero the loss accumulator
  k_emis<<<2048, 192, 0, stream>>>(hs, W, bias, emis);
  k_scan<<<128, 64, 0, stream>>>(emis, msk, trans, sv, ev, logZ, out + 1);
  k_loss<<<64, 64, 0, stream>>>(emis, msk, lab, trans, sv, ev, logZ, out);
}